// Round 7
// baseline (332.254 us; speedup 1.0000x reference)
//
#include <hip/hip_runtime.h>

using f32x4  = __attribute__((ext_vector_type(4)))  float;
using f32x2  = __attribute__((ext_vector_type(2)))  float;
using f32x16 = __attribute__((ext_vector_type(16))) float;
using s16x8  = __attribute__((ext_vector_type(8)))  short;
using u16x4  = __attribute__((ext_vector_type(4)))  ushort;

constexpr int NB   = 16;    // batch
constexpr int CH   = 256;   // channels
constexpr int TT   = 4096;  // time
constexpr int NT   = 128;   // tokens per tile
constexpr int HALO = 8;     // (K-1)*DIL
constexpr int XROWS = NT + HALO;     // 136
// pitch 528B = 512 + 16: row stride mod 128B = 16 -> any 8 consecutive rows
// cover all 8 16B bank slots (balanced, no extra serialization) while every
// GEMM LDS access stays base-VGPR + compile-time immediate.
constexpr int ROWB = 528;
constexpr int XBYTES = XROWS * ROWB;   // 71808
constexpr int ZOFF   = XBYTES;
constexpr int ZBYTES = NT * ROWB;      // 67584  (total 139392 B)

__device__ __forceinline__ ushort f2b(float f) {
    unsigned u; __builtin_memcpy(&u, &f, 4);
    u += 0x7FFFu + ((u >> 16) & 1u);   // RNE
    return (ushort)(u >> 16);
}
__device__ __forceinline__ float fast_sigmoid(float x) {
    return __builtin_amdgcn_rcpf(1.f + __expf(-x));
}
__device__ __forceinline__ float fast_tanh(float x) {
    return 2.f * __builtin_amdgcn_rcpf(1.f + __expf(-2.f * x)) - 1.f;
}

// Weight prep: f32 -> bf16.
// W1[m][k]: m<256 filter / m>=256 gate, k = tap*256 + in_ch.
// W2[m][i]: m<256 res / m>=256 skip.
__global__ __launch_bounds__(512)
void prep_w(const float* __restrict__ wf, const float* __restrict__ wg,
            const float* __restrict__ wr, const float* __restrict__ wsk,
            ushort* __restrict__ W1, ushort* __restrict__ W2) {
    int g = blockIdx.x * 512 + threadIdx.x;
    if (g < 512 * 64) {                       // W1: 512 rows x 64 threads (4 i each)
        int m = g >> 6, i0 = (g & 63) * 4;
        const float* src = (m < 256) ? wf + ((size_t)m << 9)
                                     : wg + ((size_t)(m - 256) << 9);
        f32x4 a = *(const f32x4*)&src[i0 * 2];
        f32x4 c = *(const f32x4*)&src[i0 * 2 + 4];
        u16x4 t0v = { f2b(a[0]), f2b(a[2]), f2b(c[0]), f2b(c[2]) };
        u16x4 t1v = { f2b(a[1]), f2b(a[3]), f2b(c[1]), f2b(c[3]) };
        *(u16x4*)&W1[(size_t)m * 512 + i0]       = t0v;   // tap 0 block
        *(u16x4*)&W1[(size_t)m * 512 + 256 + i0] = t1v;   // tap 1 block
    } else {                                  // W2: 512 rows x 64 threads
        int g2 = g - 512 * 64;
        int m = g2 >> 6, i0 = (g2 & 63) * 4;
        const float* src = (m < 256) ? wr + ((size_t)m << 8)
                                     : wsk + ((size_t)(m - 256) << 8);
        f32x4 a = *(const f32x4*)&src[i0];
        u16x4 o = { f2b(a[0]), f2b(a[1]), f2b(a[2]), f2b(a[3]) };
        *(u16x4*)&W2[(size_t)m * 256 + i0] = o;
    }
}

// 512 blocks x 1024 threads (16 waves, 4/SIMD). Wave grid: 8 channel-stripes
// x 2 token-halves. Wave = 64 tokens x {32 filter ch + 32 gate ch} using
// mfma_f32_32x32x16_bf16: acc = 4 x f32x16 = 64 AGPR, and each 1KB LDS
// A-read feeds 2048 FLOP/lane-byte (2x the 16x16x32 rate).
// A = x (M = tokens, row = lane&31, k = (lane>>5)*8+e),
// B = W (N = channels, col = lane&31, k = (lane>>5)*8+e),
// D: col = lane&31 = channel, row = (reg&3)+8*(reg>>2)+4*(lane>>5) = token.
__global__ __launch_bounds__(1024, 4)
void fused_block(const float* __restrict__ x,
                 const ushort* __restrict__ W1, const ushort* __restrict__ W2,
                 const float* __restrict__ b_filt, const float* __restrict__ b_gate,
                 const float* __restrict__ b_res,  const float* __restrict__ b_skip,
                 float* __restrict__ out) {
    __shared__ __align__(16) char lds[XBYTES + ZBYTES];   // 139392 B

    const int tid = threadIdx.x;
    const int b  = blockIdx.x >> 5;           // 32 tiles per batch
    const int t0 = (blockIdx.x & 31) * NT;
    const float* X = x + (size_t)b * CH * TT;
    const int tg0 = t0 - HALO;

    // ---------------- stage x (f32 -> bf16, transposed) ----------------
    {
        const int tc  = tid & 7;          // token chunk (4 tokens) within 32
        const int cp  = tid >> 3;         // channel pair 0..127
        const float* Xa = X + (size_t)(cp * 2) * TT;
        const float* Xb = Xa + TT;
        #pragma unroll
        for (int it = 0; it < 4; ++it) {  // rows 0..127
            int tg = tg0 + it * 32 + tc * 4;
            f32x4 va = (f32x4){0.f,0.f,0.f,0.f}, vb = va;
            if (tg >= 0) { va = *(const f32x4*)&Xa[tg]; vb = *(const f32x4*)&Xb[tg]; }
            #pragma unroll
            for (int e = 0; e < 4; ++e) {
                int row = it * 32 + tc * 4 + e;
                unsigned pk = (unsigned)f2b(va[e]) | ((unsigned)f2b(vb[e]) << 16);
                *(unsigned*)(lds + row * ROWB + cp * 4) = pk;
            }
        }
        // tail rows 128..135 = tokens t0+120..t0+127 (always in range)
        int c = tid & 255, h = tid >> 8;  // h 0..3 -> 2 tokens each
        f32x2 v = *(const f32x2*)&X[(size_t)c * TT + tg0 + 128 + h * 2];
        #pragma unroll
        for (int e = 0; e < 2; ++e)
            *(ushort*)(lds + (128 + h * 2 + e) * ROWB + c * 2) = f2b(v[e]);
    }
    __syncthreads();

    const int wv = tid >> 6, lane = tid & 63;
    const int l32 = lane & 31, hi = lane >> 5;
    const int stripe = wv & 7;            // channel stripe 0..7
    const int tb = (wv >> 3) * 64;        // token-half base (0 or 64)
    const int ch0 = stripe * 32;

    // B-operand row pointers (per-lane W rows, 16B fragments at k-offsets)
    const ushort* W1F = W1 + (size_t)(ch0 + l32) * 512 + hi * 8;
    const ushort* W1G = W1F + (size_t)256 * 512;          // gate rows
    const ushort* W2R = W2 + (size_t)(ch0 + l32) * 256 + hi * 8;
    const ushort* W2S = W2R + (size_t)256 * 256;          // skip rows

    // A-operand LDS bases: all reads are base + immediate
    const char* xbase = lds + (tb + l32) * ROWB + hi * 16;
    const char* zbase = lds + ZOFF + (tb + l32) * ROWB + hi * 16;

    f32x16 acc00, acc01, acc10, acc11;    // [m-tile][F/G]
    #pragma unroll
    for (int r = 0; r < 16; ++r) { acc00[r] = 0.f; acc01[r] = 0.f;
                                   acc10[r] = 0.f; acc11[r] = 0.f; }

    // ---------------- GEMM1: 32 k-steps of K=16 (K-total 512) ----------------
    s16x8 wcF = *(const s16x8*)&W1F[0];
    s16x8 wcG = *(const s16x8*)&W1G[0];

    #pragma unroll
    for (int ks = 0; ks < 32; ++ks) {
        s16x8 wnF, wnG;
        if (ks < 31) {                       // distance-1 prefetch (L2-hot)
            wnF = *(const s16x8*)&W1F[(ks + 1) * 16];
            wnG = *(const s16x8*)&W1G[(ks + 1) * 16];
        }
        const int tap = ks >> 4, ci = ks & 15;
        s16x8 a0 = *(const s16x8*)(xbase + (tap * 8)      * ROWB + ci * 32);
        s16x8 a1 = *(const s16x8*)(xbase + (32 + tap * 8) * ROWB + ci * 32);
        acc00 = __builtin_amdgcn_mfma_f32_32x32x16_bf16(a0, wcF, acc00, 0, 0, 0);
        acc01 = __builtin_amdgcn_mfma_f32_32x32x16_bf16(a0, wcG, acc01, 0, 0, 0);
        acc10 = __builtin_amdgcn_mfma_f32_32x32x16_bf16(a1, wcF, acc10, 0, 0, 0);
        acc11 = __builtin_amdgcn_mfma_f32_32x32x16_bf16(a1, wcG, acc11, 0, 0, 0);
        if (ks < 31) { wcF = wnF; wcG = wnG; }
    }

    // preload GEMM2's first W fragments; L2 latency hides under activations
    s16x8 wc2R = *(const s16x8*)&W2R[0];
    s16x8 wc2S = *(const s16x8*)&W2S[0];

    // NO barrier here: z region is disjoint from x region, and activations
    // consume only this wave's own accumulators.

    // ---------------- activations -> z (bf16), separate LDS region ----------------
    {
        const int zc = ch0 + l32;
        const float bfv = b_filt[zc], bgv = b_gate[zc];
        char* zw = lds + ZOFF + zc * 2 + (tb + 4 * hi) * ROWB;
        #pragma unroll
        for (int r = 0; r < 16; ++r) {
            float fv0 = acc00[r] + bfv, gv0 = acc01[r] + bgv;
            int row0 = ((r & 3) + 8 * (r >> 2)) * ROWB;
            *(ushort*)(zw + row0) = f2b(fast_tanh(fv0) * fast_sigmoid(gv0));
            float fv1 = acc10[r] + bfv, gv1 = acc11[r] + bgv;
            *(ushort*)(zw + row0 + 32 * ROWB) = f2b(fast_tanh(fv1) * fast_sigmoid(gv1));
        }
    }
    __syncthreads();   // all z written before GEMM2 reads all channels

    // ---------------- GEMM2: 16 k-steps of K=16 (K-total 256) ----------------
    #pragma unroll
    for (int r = 0; r < 16; ++r) { acc00[r] = 0.f; acc01[r] = 0.f;
                                   acc10[r] = 0.f; acc11[r] = 0.f; }

    #pragma unroll
    for (int ks = 0; ks < 16; ++ks) {
        s16x8 wnR, wnS;
        if (ks < 15) {
            wnR = *(const s16x8*)&W2R[(ks + 1) * 16];
            wnS = *(const s16x8*)&W2S[(ks + 1) * 16];
        }
        s16x8 a0 = *(const s16x8*)(zbase + ks * 32);
        s16x8 a1 = *(const s16x8*)(zbase + 32 * ROWB + ks * 32);
        acc00 = __builtin_amdgcn_mfma_f32_32x32x16_bf16(a0, wc2R, acc00, 0, 0, 0);
        acc01 = __builtin_amdgcn_mfma_f32_32x32x16_bf16(a0, wc2S, acc01, 0, 0, 0);
        acc10 = __builtin_amdgcn_mfma_f32_32x32x16_bf16(a1, wc2R, acc10, 0, 0, 0);
        acc11 = __builtin_amdgcn_mfma_f32_32x32x16_bf16(a1, wc2S, acc11, 0, 0, 0);
        if (ks < 15) { wc2R = wnR; wc2S = wnS; }
    }

    // ---------------- epilogue: vectorized f32x4 stores ----------------
    const size_t OUT1 = (size_t)NB * CH * TT;
    {
        const int ch = ch0 + l32;
        const float br = b_res[ch], bs = b_skip[ch];
        const float* Xc = X + (size_t)ch * TT + t0 + tb + hi * 4;
        float* O0 = out + ((size_t)(b * CH + ch)) * TT + t0 + tb + hi * 4;
        float* O1 = O0 + OUT1;
        #pragma unroll
        for (int q = 0; q < 4; ++q) {
            // m-tile 0: tokens tb + 8q + 4hi + 0..3
            {
                const int toff = q * 8;
                f32x4 xv = *(const f32x4*)&Xc[toff];
                f32x4 o0, o1;
                #pragma unroll
                for (int j = 0; j < 4; ++j) {
                    o0[j] = xv[j] + acc00[q * 4 + j] + br;
                    o1[j] = acc01[q * 4 + j] + bs;
                }
                *(f32x4*)&O0[toff] = o0;
                *(f32x4*)&O1[toff] = o1;
            }
            // m-tile 1: +32 tokens
            {
                const int toff = 32 + q * 8;
                f32x4 xv = *(const f32x4*)&Xc[toff];
                f32x4 o0, o1;
                #pragma unroll
                for (int j = 0; j < 4; ++j) {
                    o0[j] = xv[j] + acc10[q * 4 + j] + br;
                    o1[j] = acc11[q * 4 + j] + bs;
                }
                *(f32x4*)&O0[toff] = o0;
                *(f32x4*)&O1[toff] = o1;
            }
        }
    }
}

extern "C" void kernel_launch(void* const* d_in, const int* in_sizes, int n_in,
                              void* d_out, int out_size, void* d_ws, size_t ws_size,
                              hipStream_t stream) {
    const float* x   = (const float*)d_in[0];
    const float* wf  = (const float*)d_in[1];
    const float* bfi = (const float*)d_in[2];
    const float* wg  = (const float*)d_in[3];
    const float* bg  = (const float*)d_in[4];
    const float* wr  = (const float*)d_in[5];
    const float* br  = (const float*)d_in[6];
    const float* wsk = (const float*)d_in[7];
    const float* bs  = (const float*)d_in[8];

    ushort* W1 = (ushort*)d_ws;                  // 512*512 bf16
    ushort* W2 = W1 + 512 * 512;                 // 512*256 bf16

    prep_w<<<128, 512, 0, stream>>>(wf, wg, wr, wsk, W1, W2);

    const int nBlocks = NB * (TT / NT);          // 512
    fused_block<<<nBlocks, 1024, 0, stream>>>(x, W1, W2, bfi, bg, br, bs,
                                              (float*)d_out);
}